// Round 14
// baseline (1492.356 us; speedup 1.0000x reference)
//
#include <hip/hip_runtime.h>
#include <hip/hip_bf16.h>
#include <stdint.h>

typedef __bf16 bf16_t;
typedef __bf16 bf16x8 __attribute__((ext_vector_type(8)));
typedef float f32x4 __attribute__((ext_vector_type(4)));

#define AS1(p) ((const __attribute__((address_space(1))) void*)(uintptr_t)(p))
#define AS3(p) ((__attribute__((address_space(3))) void*)(uintptr_t)(p))

__device__ __forceinline__ void gload16(const bf16_t* g, bf16_t* l) {
  __builtin_amdgcn_global_load_lds(AS1(g), AS3(l), 16, 0, 0);
}

#define SB()      __builtin_amdgcn_sched_barrier(0);
#define BARR()    { __builtin_amdgcn_s_barrier(); __builtin_amdgcn_sched_barrier(0); }
#define VMCNT(n)  { asm volatile("s_waitcnt vmcnt(" #n ")" ::: "memory"); __builtin_amdgcn_sched_barrier(0); }
#define LGKM(n)   { asm volatile("s_waitcnt lgkmcnt(" #n ")" ::: "memory"); __builtin_amdgcn_sched_barrier(0); }

// == 256x256 GEMM core (B^T form): R8 read-pipeline + 4-slot ring (3-window prefetch) ==
// C[m][n] = sum_k A[m][k]*B[n][k]. 512 threads = 8 waves (2M x 4N), per-wave 128x64.
// K in 32-wide halves; LDS ring: 4 slots x 32KB {A 16K | B 16K} = 128 KiB.
// Half layout [256 rows][32 k] bf16, XOR swizzle byte^=((byte>>7)&7)<<4 (write: linear
// LDS dest + pre-swizzled global source; read: same XOR) -> 0 bank conflicts (proven).
// Window w: vmcnt(8) [retire slot w; slots w+1,w+2 stay in flight] -> BAR -> reads
// (B 4 + A-qm0 4) -> stage slot w+3 (4 gloads) -> reads (A-qm1 4) -> lgkm(4) ->
// 16 MFMA -> lgkm(0) -> 16 MFMA. Issue->drain distance = 3 windows (~930cy >= HBM
// ~900cy latency) vs R8's 2 (~620cy): covers the HBM-miss exposure R8 left at each
// wait. Ledger (in-order vmcnt, only gload_lds in loop): pre-wait outstanding = 12;
// vmcnt(8) retires exactly slot w's 4. Tail: 8/4/0. WAR: stage(w+3) targets slot
// (w-1)&3 whose reads were lgkm0-drained before BAR(w); stage issued after BAR(w).
// RAW: every wave's vmcnt(8) precedes the shared barrier.
__device__ __forceinline__ void gemm256(const bf16_t* __restrict__ A, int lda,
                                        const bf16_t* __restrict__ B, int ldb,
                                        int nt, f32x4 acc[8][4], bf16_t* lds) {
  const int t = (int)threadIdx.x;
  const int lane = t & 63, wv = t >> 6;
  const int wr = wv >> 2, wc = wv & 3;
  const int fr = lane & 15, fq = lane >> 4;
  char* ldsb = (char*)lds;

  const int s0 = (t * 16) ^ (((t >> 3) & 7) << 4);
  const int r0 = s0 >> 6, q0 = (s0 >> 4) & 3;
  const bf16_t* gA0 = A + (size_t)r0 * lda + q0 * 8;
  const bf16_t* gA1 = gA0 + (size_t)128 * lda;
  const bf16_t* gB0 = B + (size_t)r0 * ldb + q0 * 8;
  const bf16_t* gB1 = gB0 + (size_t)128 * ldb;

  const int swz = (fr * 64 + fq * 16) ^ (((fr >> 1) & 7) << 4);
  const int abase = wr * 8192 + swz;          // + slot*32768 + qm*4096 (bytes)
  const int bbase = 16384 + wc * 4096 + swz;  // + slot*32768 (bytes)

  bf16x8 bb[4], aa0[4], aa1[4];

#define STAGE(sl, kof) { \
    bf16_t* _d = lds + (sl) * 16384; \
    gload16(gA0 + (kof), _d + t * 8); \
    gload16(gA1 + (kof), _d + 4096 + t * 8); \
    gload16(gB0 + (kof), _d + 8192 + t * 8); \
    gload16(gB1 + (kof), _d + 12288 + t * 8); \
  } SB()
#define READ_B(sl) { \
    const char* _b = ldsb + (sl) * 32768 + bbase; \
    _Pragma("unroll") for (int n = 0; n < 4; ++n) bb[n] = *(const bf16x8*)(_b + n * 1024); }
#define READ_A(sl, qm, dst) { \
    const char* _a = ldsb + (sl) * 32768 + abase + (qm) * 4096; \
    _Pragma("unroll") for (int i = 0; i < 4; ++i) dst[i] = *(const bf16x8*)(_a + i * 1024); }
#define MFMA16(dst, qm) { \
    __builtin_amdgcn_s_setprio(1); \
    _Pragma("unroll") for (int i = 0; i < 4; ++i) \
      _Pragma("unroll") for (int n = 0; n < 4; ++n) \
        acc[(qm) * 4 + i][n] = __builtin_amdgcn_mfma_f32_16x16x32_bf16(dst[i], bb[n], acc[(qm) * 4 + i][n], 0, 0, 0); \
    __builtin_amdgcn_s_setprio(0); }
#define WINDOW_BODY(sl, DOSTAGE) \
    READ_B(sl) READ_A(sl, 0, aa0) \
    DOSTAGE \
    READ_A(sl, 1, aa1) \
    LGKM(4) MFMA16(aa0, 0) \
    LGKM(0) MFMA16(aa1, 1)

  const int H = nt * 2;  // number of 32-wide k-halves (>= 8 for all call sites)
  STAGE(0, 0) STAGE(1, 32) STAGE(2, 64)
  int kof = 96;
  for (int w = 0; w + 3 < H; ++w, kof += 32) {
    const int sl = w & 3;
    VMCNT(8) BARR()
    WINDOW_BODY(sl, STAGE((w + 3) & 3, kof))
  }
  { const int sl = (H - 3) & 3; VMCNT(8) BARR() WINDOW_BODY(sl, ) }
  { const int sl = (H - 2) & 3; VMCNT(4) BARR() WINDOW_BODY(sl, ) }
  { const int sl = (H - 1) & 3; VMCNT(0) BARR() WINDOW_BODY(sl, ) }
#undef STAGE
#undef READ_B
#undef READ_A
#undef MFMA16
#undef WINDOW_BODY
}

#define EPI_VARS \
  const int t = (int)threadIdx.x; \
  const int lane = t & 63, w = t >> 6; \
  const int wr = w >> 2, wc = w & 3; \
  const int fr = lane & 15, fq = lane >> 4;

#define ZERO8x4(acc) \
  _Pragma("unroll") for (int _i = 0; _i < 8; ++_i) \
  _Pragma("unroll") for (int _j = 0; _j < 4; ++_j) { f32x4 _z = {0.f,0.f,0.f,0.f}; acc[_i][_j] = _z; }

// ---------------- conversions ----------------
__global__ void k_cvt(const float* __restrict__ s, bf16_t* __restrict__ d, long n8) {
  long i = (long)blockIdx.x * blockDim.x + threadIdx.x;
  long st = (long)gridDim.x * blockDim.x;
  for (; i < n8; i += st) {
    const float4* sp = (const float4*)(s + i * 8);
    float4 a = sp[0], b = sp[1];
    bf16x8 v;
    v[0] = (__bf16)a.x; v[1] = (__bf16)a.y; v[2] = (__bf16)a.z; v[3] = (__bf16)a.w;
    v[4] = (__bf16)b.x; v[5] = (__bf16)b.y; v[6] = (__bf16)b.z; v[7] = (__bf16)b.w;
    *(bf16x8*)(d + i * 8) = v;
  }
}

// merged weight conversion: [Wq|Wk|Wv|Wo] (4 x 4194304 fp32) -> contiguous bf16 dst
__global__ void k_cvtw(const float* __restrict__ Wq, const float* __restrict__ Wk,
                       const float* __restrict__ Wv, const float* __restrict__ Wo,
                       bf16_t* __restrict__ d) {
  long i = (long)blockIdx.x * blockDim.x + threadIdx.x;
  long st = (long)gridDim.x * blockDim.x;
  for (; i < 2097152L; i += st) {
    int r = (int)(i >> 19);
    const float* s = (r == 0 ? Wq : r == 1 ? Wk : r == 2 ? Wv : Wo) + (i & 524287L) * 8;
    float4 a = ((const float4*)s)[0], b = ((const float4*)s)[1];
    bf16x8 v;
    v[0] = (__bf16)a.x; v[1] = (__bf16)a.y; v[2] = (__bf16)a.z; v[3] = (__bf16)a.w;
    v[4] = (__bf16)b.x; v[5] = (__bf16)b.y; v[6] = (__bf16)b.z; v[7] = (__bf16)b.w;
    *(bf16x8*)(d + i * 8) = v;
  }
}

__global__ void k_fill(float* o, float v, long n) {
  long i = (long)blockIdx.x * blockDim.x + threadIdx.x;
  long st = (long)gridDim.x * blockDim.x;
  for (; i < n; i += st) o[i] = v;
}

// ---------------- GEMM 1: QKV projection (256-tile) ----------------
__global__ __launch_bounds__(512, 2) void k_qkv256(
    const bf16_t* __restrict__ xb, const bf16_t* __restrict__ Wb,
    const float* __restrict__ bq, const float* __restrict__ bk, const float* __restrict__ bv,
    bf16_t* __restrict__ Q, bf16_t* __restrict__ K, bf16_t* __restrict__ Vt) {
  __shared__ __align__(16) bf16_t lds[65536];
  int bid = (int)blockIdx.x;
  int id = (bid & 7) * 384 + (bid >> 3);  // XCD-bijective swizzle (3072 = 8*384)
  EPI_VARS
  f32x4 acc[8][4];
  ZERO8x4(acc)

  bool vmode = id >= 2048;
  int mt = 0, ntile = 0, tok = 0, wm = 0;
  const bf16_t *Ap, *Bp;
  if (!vmode) {
    mt = id & 127; ntile = id >> 7;  // B-panel-major: resident blocks share W panel
    Ap = xb + (size_t)mt * 256 * 2048;
    Bp = Wb + (size_t)ntile * 256 * 2048;
  } else {
    int vb = id - 2048;
    tok = vb & 127; wm = vb >> 7;
    Ap = Wb + (size_t)(16 + wm) * 256 * 2048;
    Bp = xb + (size_t)tok * 256 * 2048;
  }
  gemm256(Ap, 2048, Bp, 2048, 32, acc, lds);

  if (!vmode) {
    int sel = ntile >> 3;  // 0 -> Q, 1 -> K
    const float* bias = sel ? bk : bq;
    bf16_t* dst = sel ? K : Q;
    int cbase = (ntile & 7) * 256 + wc * 64;
#pragma unroll
    for (int ni = 0; ni < 4; ++ni) {
      int c2 = cbase + ni * 16 + fr;  // [0,2048)
      int h = c2 >> 10, d = c2 & 1023;
      float bb = bias[c2];
#pragma unroll
      for (int mi = 0; mi < 8; ++mi) {
        f32x4 a = acc[mi][ni];
#pragma unroll
        for (int r = 0; r < 4; ++r) {
          int m = mt * 256 + wr * 128 + mi * 16 + fq * 4 + r;
          int b = m >> 10, tk = m & 1023;
          dst[(((size_t)(b * 2 + h) << 10) + tk) * 1024 + d] = (bf16_t)(a[r] + bb);
        }
      }
    }
  } else {
#pragma unroll
    for (int mi = 0; mi < 8; ++mi) {
#pragma unroll
      for (int r = 0; r < 4; ++r) {
        int gd = wm * 256 + wr * 128 + mi * 16 + fq * 4 + r;  // [0,2048)
        int h = gd >> 10, dd = gd & 1023;
        float bb = bv[gd];
#pragma unroll
        for (int ni = 0; ni < 4; ++ni) {
          int m = tok * 256 + wc * 64 + ni * 16 + fr;
          int b = m >> 10, tk = m & 1023;
          Vt[(((size_t)(b * 2 + h) << 10) + dd) * 1024 + tk] = (bf16_t)(acc[mi][ni][r] + bb);
        }
      }
    }
  }
}

// ---------------- GEMM 2: S = Q K^T * scale (lower-tri 256-tiles, bf16 out) --------
__global__ __launch_bounds__(512, 2) void k_s256(const bf16_t* __restrict__ Q,
                                                 const bf16_t* __restrict__ K,
                                                 bf16_t* __restrict__ S, int pbase) {
  __shared__ __align__(16) bf16_t lds[65536];
  int id = (int)blockIdx.x;
  int pc = id / 10, rem = id % 10;
  int ti = 0;
  while (rem > ti) { rem -= ti + 1; ++ti; }
  int tj = rem;
  size_t p = (size_t)(pbase + pc);
  EPI_VARS
  f32x4 acc[8][4];
  ZERO8x4(acc)
  gemm256(Q + (p << 20) + (size_t)ti * 256 * 1024, 1024,
          K + (p << 20) + (size_t)tj * 256 * 1024, 1024, 16, acc, lds);
  bf16_t* Sp = S + ((size_t)pc << 20);
  const float scale = 0.022097086912079608f;  // 1/sqrt(2048)
#pragma unroll
  for (int mi = 0; mi < 8; ++mi)
#pragma unroll
    for (int ni = 0; ni < 4; ++ni) {
      int col = tj * 256 + wc * 64 + ni * 16 + fr;
      f32x4 a = acc[mi][ni];
#pragma unroll
      for (int r = 0; r < 4; ++r) {
        int row = ti * 256 + wr * 128 + mi * 16 + fq * 4 + r;
        Sp[((size_t)row << 10) + col] = (bf16_t)(a[r] * scale);
      }
    }
}

// --- softmax: one ROW per wave, vectorized bf16x8, causal, IN-PLACE (P == S) ---
__global__ __launch_bounds__(256) void k_softmax(const bf16_t* __restrict__ S,
                                                 bf16_t* __restrict__ P) {
  int gw = (int)blockIdx.x * 4 + ((int)threadIdx.x >> 6);
  int pc = gw >> 10, row = gw & 1023;
  int lane = (int)threadIdx.x & 63;
  const bf16_t* s = S + ((size_t)pc << 20) + ((size_t)row << 10);
  bf16_t* p = P + ((size_t)pc << 20) + ((size_t)row << 10);
  int cend = ((row >> 8) + 1) << 8;  // 256-aligned (PV K-tile width)
  bf16x8 v0 = *(const bf16x8*)(s + lane * 8);
  bf16x8 v1 = *(const bf16x8*)(s + 512 + lane * 8);
  float x[16];
  float mx = -1e30f;
#pragma unroll
  for (int j = 0; j < 8; ++j) {
    int c0 = lane * 8 + j, c1 = 512 + lane * 8 + j;
    x[j]     = (c0 <= row) ? (float)v0[j] : -1e30f;
    x[8 + j] = (c1 <= row) ? (float)v1[j] : -1e30f;
    mx = fmaxf(mx, fmaxf(x[j], x[8 + j]));
  }
  for (int o = 32; o > 0; o >>= 1) mx = fmaxf(mx, __shfl_xor(mx, o));
  float sum = 0.f;
#pragma unroll
  for (int j = 0; j < 16; ++j) {
    x[j] = (x[j] > -1e29f) ? __expf(x[j] - mx) : 0.f;
    sum += x[j];
  }
  for (int o = 32; o > 0; o >>= 1) sum += __shfl_xor(sum, o);
  float inv = 1.f / sum;
  bf16x8 o0, o1;
#pragma unroll
  for (int j = 0; j < 8; ++j) {
    o0[j] = (bf16_t)(x[j] * inv);
    o1[j] = (bf16_t)(x[8 + j] * inv);
  }
  if (lane * 8 < cend)       *(bf16x8*)(p + lane * 8) = o0;
  if (512 + lane * 8 < cend) *(bf16x8*)(p + 512 + lane * 8) = o1;
}

// ---------------- GEMM 3: O = P * V (V pre-transposed; causal-shortened K) ---------
__global__ __launch_bounds__(512, 2) void k_pv256(const bf16_t* __restrict__ P,
                                                  const bf16_t* __restrict__ Vt,
                                                  bf16_t* __restrict__ O, int pbase) {
  __shared__ __align__(16) bf16_t lds[65536];
  int id = (int)blockIdx.x;
  int pc = id >> 4, rem = id & 15;
  int ti = rem >> 2, dj = rem & 3;
  size_t p = (size_t)(pbase + pc);
  EPI_VARS
  f32x4 acc[8][4];
  ZERO8x4(acc)
  gemm256(P + ((size_t)pc << 20) + (size_t)ti * 256 * 1024, 1024,
          Vt + (p << 20) + (size_t)dj * 256 * 1024, 1024, (ti + 1) * 4, acc, lds);
  int b = (int)(p >> 1), h = (int)(p & 1);
#pragma unroll
  for (int mi = 0; mi < 8; ++mi)
#pragma unroll
    for (int ni = 0; ni < 4; ++ni) {
      int dcol = dj * 256 + wc * 64 + ni * 16 + fr;
      f32x4 a = acc[mi][ni];
#pragma unroll
      for (int r = 0; r < 4; ++r) {
        int tk = ti * 256 + wr * 128 + mi * 16 + fq * 4 + r;
        O[(((size_t)b << 10) + tk) * 2048 + (h << 10) + dcol] = (bf16_t)a[r];
      }
    }
}

// ---------------- GEMM 4: out = O * Wo^T (fp32 out) ----------------
__global__ __launch_bounds__(512, 2) void k_out256(const bf16_t* __restrict__ O,
                                                   const bf16_t* __restrict__ W,
                                                   float* __restrict__ out) {
  __shared__ __align__(16) bf16_t lds[65536];
  int bid = (int)blockIdx.x;
  int id = (bid & 7) * 128 + (bid >> 3);  // XCD swizzle (1024 = 8*128)
  int mt = id & 127, ntile = id >> 7;     // B-panel-major
  EPI_VARS
  f32x4 acc[8][4];
  ZERO8x4(acc)
  gemm256(O + (size_t)mt * 256 * 2048, 2048, W + (size_t)ntile * 256 * 2048, 2048, 32, acc, lds);
#pragma unroll
  for (int mi = 0; mi < 8; ++mi)
#pragma unroll
    for (int ni = 0; ni < 4; ++ni) {
      int col = ntile * 256 + wc * 64 + ni * 16 + fr;
      f32x4 a = acc[mi][ni];
#pragma unroll
      for (int r = 0; r < 4; ++r) {
        int row = mt * 256 + wr * 128 + mi * 16 + fq * 4 + r;
        out[(size_t)row * 2048 + col] = a[r];
      }
    }
}

// ---------------- launch ----------------
extern "C" void kernel_launch(void* const* d_in, const int* in_sizes, int n_in,
                              void* d_out, int out_size, void* d_ws, size_t ws_size,
                              hipStream_t stream) {
  const float* x  = (const float*)d_in[0];
  const float* Wq = (const float*)d_in[1];
  const float* bq = (const float*)d_in[2];
  const float* Wk = (const float*)d_in[3];
  const float* bk = (const float*)d_in[4];
  const float* Wv = (const float*)d_in[5];
  const float* bv = (const float*)d_in[6];
  const float* Wo = (const float*)d_in[7];
  float* out = (float*)d_out;

  const size_t MiB = 1ull << 20;
  char* w = (char*)d_ws;
  bf16_t* xb    = (bf16_t*)w;               // 128 MiB, reused as O after QKV
  bf16_t* Ob    = xb;
  bf16_t* Qb    = (bf16_t*)(w + 128 * MiB); // 128 MiB
  bf16_t* Kb    = (bf16_t*)(w + 256 * MiB); // 128 MiB
  bf16_t* Vt    = (bf16_t*)(w + 384 * MiB); // 128 MiB (transposed V)
  bf16_t* Wqkvb = (bf16_t*)(w + 512 * MiB); // 32 MiB [Wq;Wk;Wv;Wo] contiguous
  bf16_t* Wob   = (bf16_t*)(w + 536 * MiB); // = Wqkvb + 24 MiB
  bf16_t* Sc    = (bf16_t*)(w + 544 * MiB); // NP * 2 MiB (bf16; softmax in-place)

  size_t rem = ws_size > 544 * MiB ? ws_size - 544 * MiB : 0;
  int NP = (int)(rem / (2 * MiB));
  if (NP > 64) NP = 64;
  if (NP < 1) {
    k_fill<<<2048, 256, 0, stream>>>(out, (float)(ws_size >> 20), (long)out_size);
    return;
  }

  // conversions to bf16 (x; then all four weights in one launch - dst contiguous)
  k_cvt<<<2048, 256, 0, stream>>>(x, xb, 8388608L);
  k_cvtw<<<2048, 256, 0, stream>>>(Wq, Wk, Wv, Wo, Wqkvb);

  // QKV projection (Q,K normal layout; V transposed)
  k_qkv256<<<3072, 512, 0, stream>>>(xb, Wqkvb, bq, bk, bv, Qb, Kb, Vt);

  // attention, chunked over (b,h) pairs to bound scratch (softmax in-place: P == S)
  for (int base = 0; base < 64; base += NP) {
    int np = (64 - base) < NP ? (64 - base) : NP;
    k_s256<<<np * 10, 512, 0, stream>>>(Qb, Kb, Sc, base);
    k_softmax<<<np * 256, 256, 0, stream>>>(Sc, Sc);
    k_pv256<<<np * 16, 512, 0, stream>>>(Sc, Vt, Ob, base);
  }

  // output projection
  k_out256<<<1024, 512, 0, stream>>>(Ob, Wob, out);
}

// Round 15
// 1474.649 us; speedup vs baseline: 1.0120x; 1.0120x over previous
//
#include <hip/hip_runtime.h>
#include <hip/hip_bf16.h>
#include <stdint.h>

typedef __bf16 bf16_t;
typedef __bf16 bf16x8 __attribute__((ext_vector_type(8)));
typedef float f32x4 __attribute__((ext_vector_type(4)));

#define AS1(p) ((const __attribute__((address_space(1))) void*)(uintptr_t)(p))
#define AS3(p) ((__attribute__((address_space(3))) void*)(uintptr_t)(p))

__device__ __forceinline__ void gload16(const bf16_t* g, bf16_t* l) {
  __builtin_amdgcn_global_load_lds(AS1(g), AS3(l), 16, 0, 0);
}

#define SB()      __builtin_amdgcn_sched_barrier(0);
#define BARR()    { __builtin_amdgcn_s_barrier(); __builtin_amdgcn_sched_barrier(0); }
#define VMCNT(n)  { asm volatile("s_waitcnt vmcnt(" #n ")" ::: "memory"); __builtin_amdgcn_sched_barrier(0); }
#define LGKM(n)   { asm volatile("s_waitcnt lgkmcnt(" #n ")" ::: "memory"); __builtin_amdgcn_sched_barrier(0); }

// == 256x256 GEMM core (B^T form), 16-WAVE variant of the R8 counted 2-window core ==
// C[m][n] = sum_k A[m][k]*B[n][k]. 1024 threads = 16 waves (4M x 4N), per-wave 64x64.
// Same tile, same 128 KiB LDS (A kh0|A kh1|B kh0|B kh1 x 2 bufs), same XOR swizzle
// (write: linear dest + pre-swizzled global source; read: same XOR; swizzle term
// re-verified lane-constant for 64-row wave tiles) -> 0 bank conflicts.
// WHY 16 waves: all R3-R14 variants ran 2 waves/SIMD in barrier lockstep -> each
// wave's LDS-read latency/MFMA gaps covered by only 1 other wave (47% MfmaUtil
// plateau). 16 waves = 4/SIMD (acc[4][4]=64 regs -> ~120 unified regs <= 128 cap,
// pool 512/SIMD) doubles within-window latency hiding; CU-wide work unchanged.
// Stage unit = 1 gload/thread (1024 x 16B = 16KB half). Ledger (in-order vmcnt,
// only gload_lds in loop): prologue 4 outstanding {A0,B0,A1,B1}; each window's
// vmcnt(2) retires exactly its half's {A,B} (issued 2 windows earlier). Tail 2->0.
// WAR: stage into (cb^1,kh) follows BAR postdating all waves' lgkm0-drained reads
// of that region (prev tile). RAW: every wave's vmcnt(2) precedes the shared BAR.
__device__ __forceinline__ void gemm256(const bf16_t* __restrict__ A, int lda,
                                        const bf16_t* __restrict__ B, int ldb,
                                        int nt, f32x4 acc[4][4], bf16_t* lds) {
  const int t = (int)threadIdx.x;      // 0..1023
  const int lane = t & 63, wv = t >> 6;  // wv 0..15
  const int wr = wv >> 2, wc = wv & 3;   // 4M x 4N, wave tile 64x64
  const int fr = lane & 15, fq = lane >> 4;
  char* ldsb = (char*)lds;

  // staging: thread t writes LDS bytes [t*16,+16) of a 16KB half (linear);
  // global source pre-swizzled so the swizzled read sees the right data
  const int s0 = (t * 16) ^ (((t >> 3) & 7) << 4);
  const int r0 = s0 >> 6, q0 = (s0 >> 4) & 3;  // r0 0..255
  const bf16_t* gA = A + (size_t)r0 * lda + q0 * 8;
  const bf16_t* gB = B + (size_t)r0 * ldb + q0 * 8;

  // frag read bases (bytes). row = wr*64 + qm*16 + fr: swizzle bits ((row>>1)&7)
  // = ((fr>>1)&7) since wr*64 and qm*16 contribute 0 mod 8 after >>1.
  const int swz = (fr * 64 + fq * 16) ^ (((fr >> 1) & 7) << 4);
  const int abase = wr * 4096 + swz;          // + cb*65536 + kh*16384 + qm*1024
  const int bbase = 32768 + wc * 4096 + swz;  // + cb*65536 + kh*16384 + cn*1024

  bf16x8 bb[4], aaA[2], aaB[2];

#define STAGE_A(cb, kh, kof) { \
    gload16(gA + (kof) + (kh) * 32, lds + (cb) * 32768 + (kh) * 8192 + t * 8); \
  } SB()
#define STAGE_B(cb, kh, kof) { \
    gload16(gB + (kof) + (kh) * 32, lds + (cb) * 32768 + 16384 + (kh) * 8192 + t * 8); \
  } SB()
#define READ_B(cb, kh) { \
    const char* _b = ldsb + (cb) * 65536 + (kh) * 16384 + bbase; \
    _Pragma("unroll") for (int n = 0; n < 4; ++n) bb[n] = *(const bf16x8*)(_b + n * 1024); }
#define READ_A2(cb, kh, qh, dst) { \
    const char* _a = ldsb + (cb) * 65536 + (kh) * 16384 + abase + (qh) * 2048; \
    dst[0] = *(const bf16x8*)(_a); \
    dst[1] = *(const bf16x8*)(_a + 1024); }
#define MFMA8(dst, qh) { \
    __builtin_amdgcn_s_setprio(1); \
    _Pragma("unroll") for (int qi = 0; qi < 2; ++qi) \
      _Pragma("unroll") for (int n = 0; n < 4; ++n) \
        acc[(qh) * 2 + qi][n] = __builtin_amdgcn_mfma_f32_16x16x32_bf16(dst[qi], bb[n], acc[(qh) * 2 + qi][n], 0, 0, 0); \
    __builtin_amdgcn_s_setprio(0); }

  // prologue: stage tile 0 fully (4 gloads, ledger order A0,B0,A1,B1)
  STAGE_A(0, 0, 0) STAGE_B(0, 0, 0) STAGE_A(0, 1, 0) STAGE_B(0, 1, 0)

  int kof = 64;
  for (int tt = 0; tt < nt - 1; ++tt, kof += 64) {
    const int cb = tt & 1;
    // window kh0
    VMCNT(2) BARR()
    READ_B(cb, 0) READ_A2(cb, 0, 0, aaA)
    STAGE_A(cb ^ 1, 0, kof)
    READ_A2(cb, 0, 1, aaB)
    STAGE_B(cb ^ 1, 0, kof)
    LGKM(2) MFMA8(aaA, 0)
    LGKM(0) MFMA8(aaB, 1)
    // window kh1
    VMCNT(2) BARR()
    READ_B(cb, 1) READ_A2(cb, 1, 0, aaA)
    STAGE_A(cb ^ 1, 1, kof)
    READ_A2(cb, 1, 1, aaB)
    STAGE_B(cb ^ 1, 1, kof)
    LGKM(2) MFMA8(aaA, 0)
    LGKM(0) MFMA8(aaB, 1)
  }
  {  // tail tile: no staging; drain 2 then 0
    const int cb = (nt - 1) & 1;
    VMCNT(2) BARR()
    READ_B(cb, 0) READ_A2(cb, 0, 0, aaA) READ_A2(cb, 0, 1, aaB)
    LGKM(2) MFMA8(aaA, 0)
    LGKM(0) MFMA8(aaB, 1)
    VMCNT(0) BARR()
    READ_B(cb, 1) READ_A2(cb, 1, 0, aaA) READ_A2(cb, 1, 1, aaB)
    LGKM(2) MFMA8(aaA, 0)
    LGKM(0) MFMA8(aaB, 1)
  }
#undef STAGE_A
#undef STAGE_B
#undef READ_B
#undef READ_A2
#undef MFMA8
}

#define EPI_VARS \
  const int t = (int)threadIdx.x; \
  const int lane = t & 63, w = t >> 6; \
  const int wr = w >> 2, wc = w & 3; \
  const int fr = lane & 15, fq = lane >> 4;

#define ZERO4x4(acc) \
  _Pragma("unroll") for (int _i = 0; _i < 4; ++_i) \
  _Pragma("unroll") for (int _j = 0; _j < 4; ++_j) { f32x4 _z = {0.f,0.f,0.f,0.f}; acc[_i][_j] = _z; }

// ---------------- conversions ----------------
__global__ void k_cvt(const float* __restrict__ s, bf16_t* __restrict__ d, long n8) {
  long i = (long)blockIdx.x * blockDim.x + threadIdx.x;
  long st = (long)gridDim.x * blockDim.x;
  for (; i < n8; i += st) {
    const float4* sp = (const float4*)(s + i * 8);
    float4 a = sp[0], b = sp[1];
    bf16x8 v;
    v[0] = (__bf16)a.x; v[1] = (__bf16)a.y; v[2] = (__bf16)a.z; v[3] = (__bf16)a.w;
    v[4] = (__bf16)b.x; v[5] = (__bf16)b.y; v[6] = (__bf16)b.z; v[7] = (__bf16)b.w;
    *(bf16x8*)(d + i * 8) = v;
  }
}

// merged weight conversion: [Wq|Wk|Wv|Wo] (4 x 4194304 fp32) -> contiguous bf16 dst
__global__ void k_cvtw(const float* __restrict__ Wq, const float* __restrict__ Wk,
                       const float* __restrict__ Wv, const float* __restrict__ Wo,
                       bf16_t* __restrict__ d) {
  long i = (long)blockIdx.x * blockDim.x + threadIdx.x;
  long st = (long)gridDim.x * blockDim.x;
  for (; i < 2097152L; i += st) {
    int r = (int)(i >> 19);
    const float* s = (r == 0 ? Wq : r == 1 ? Wk : r == 2 ? Wv : Wo) + (i & 524287L) * 8;
    float4 a = ((const float4*)s)[0], b = ((const float4*)s)[1];
    bf16x8 v;
    v[0] = (__bf16)a.x; v[1] = (__bf16)a.y; v[2] = (__bf16)a.z; v[3] = (__bf16)a.w;
    v[4] = (__bf16)b.x; v[5] = (__bf16)b.y; v[6] = (__bf16)b.z; v[7] = (__bf16)b.w;
    *(bf16x8*)(d + i * 8) = v;
  }
}

__global__ void k_fill(float* o, float v, long n) {
  long i = (long)blockIdx.x * blockDim.x + threadIdx.x;
  long st = (long)gridDim.x * blockDim.x;
  for (; i < n; i += st) o[i] = v;
}

// ---------------- GEMM 1: QKV projection (256-tile, 16 waves) ----------------
__global__ __launch_bounds__(1024, 1) void k_qkv256(
    const bf16_t* __restrict__ xb, const bf16_t* __restrict__ Wb,
    const float* __restrict__ bq, const float* __restrict__ bk, const float* __restrict__ bv,
    bf16_t* __restrict__ Q, bf16_t* __restrict__ K, bf16_t* __restrict__ Vt) {
  __shared__ __align__(16) bf16_t lds[65536];
  int bid = (int)blockIdx.x;
  int id = (bid & 7) * 384 + (bid >> 3);  // XCD-bijective swizzle (3072 = 8*384)
  EPI_VARS
  f32x4 acc[4][4];
  ZERO4x4(acc)

  bool vmode = id >= 2048;
  int mt = 0, ntile = 0, tok = 0, wm = 0;
  const bf16_t *Ap, *Bp;
  if (!vmode) {
    mt = id & 127; ntile = id >> 7;  // B-panel-major: resident blocks share W panel
    Ap = xb + (size_t)mt * 256 * 2048;
    Bp = Wb + (size_t)ntile * 256 * 2048;
  } else {
    int vb = id - 2048;
    tok = vb & 127; wm = vb >> 7;
    Ap = Wb + (size_t)(16 + wm) * 256 * 2048;
    Bp = xb + (size_t)tok * 256 * 2048;
  }
  gemm256(Ap, 2048, Bp, 2048, 32, acc, lds);

  if (!vmode) {
    int sel = ntile >> 3;  // 0 -> Q, 1 -> K
    const float* bias = sel ? bk : bq;
    bf16_t* dst = sel ? K : Q;
    int cbase = (ntile & 7) * 256 + wc * 64;
#pragma unroll
    for (int cn = 0; cn < 4; ++cn) {
      int c2 = cbase + cn * 16 + fr;  // [0,2048)
      int h = c2 >> 10, d = c2 & 1023;
      float bb = bias[c2];
#pragma unroll
      for (int qm = 0; qm < 4; ++qm) {
        f32x4 a = acc[qm][cn];
#pragma unroll
        for (int r = 0; r < 4; ++r) {
          int m = mt * 256 + wr * 64 + qm * 16 + fq * 4 + r;
          int b = m >> 10, tk = m & 1023;
          dst[(((size_t)(b * 2 + h) << 10) + tk) * 1024 + d] = (bf16_t)(a[r] + bb);
        }
      }
    }
  } else {
#pragma unroll
    for (int qm = 0; qm < 4; ++qm) {
#pragma unroll
      for (int r = 0; r < 4; ++r) {
        int gd = wm * 256 + wr * 64 + qm * 16 + fq * 4 + r;  // [0,2048)
        int h = gd >> 10, dd = gd & 1023;
        float bb = bv[gd];
#pragma unroll
        for (int cn = 0; cn < 4; ++cn) {
          int m = tok * 256 + wc * 64 + cn * 16 + fr;
          int b = m >> 10, tk = m & 1023;
          Vt[(((size_t)(b * 2 + h) << 10) + dd) * 1024 + tk] = (bf16_t)(acc[qm][cn][r] + bb);
        }
      }
    }
  }
}

// ---------------- GEMM 2: S = Q K^T * scale (lower-tri 256-tiles, bf16 out) --------
__global__ __launch_bounds__(1024, 1) void k_s256(const bf16_t* __restrict__ Q,
                                                  const bf16_t* __restrict__ K,
                                                  bf16_t* __restrict__ S, int pbase) {
  __shared__ __align__(16) bf16_t lds[65536];
  int id = (int)blockIdx.x;
  int pc = id / 10, rem = id % 10;
  int ti = 0;
  while (rem > ti) { rem -= ti + 1; ++ti; }
  int tj = rem;
  size_t p = (size_t)(pbase + pc);
  EPI_VARS
  f32x4 acc[4][4];
  ZERO4x4(acc)
  gemm256(Q + (p << 20) + (size_t)ti * 256 * 1024, 1024,
          K + (p << 20) + (size_t)tj * 256 * 1024, 1024, 16, acc, lds);
  bf16_t* Sp = S + ((size_t)pc << 20);
  const float scale = 0.022097086912079608f;  // 1/sqrt(2048)
#pragma unroll
  for (int qm = 0; qm < 4; ++qm)
#pragma unroll
    for (int cn = 0; cn < 4; ++cn) {
      int col = tj * 256 + wc * 64 + cn * 16 + fr;
      f32x4 a = acc[qm][cn];
#pragma unroll
      for (int r = 0; r < 4; ++r) {
        int row = ti * 256 + wr * 64 + qm * 16 + fq * 4 + r;
        Sp[((size_t)row << 10) + col] = (bf16_t)(a[r] * scale);
      }
    }
}

// --- softmax: one ROW per wave, vectorized bf16x8, causal, IN-PLACE (P == S) ---
__global__ __launch_bounds__(256) void k_softmax(const bf16_t* __restrict__ S,
                                                 bf16_t* __restrict__ P) {
  int gw = (int)blockIdx.x * 4 + ((int)threadIdx.x >> 6);
  int pc = gw >> 10, row = gw & 1023;
  int lane = (int)threadIdx.x & 63;
  const bf16_t* s = S + ((size_t)pc << 20) + ((size_t)row << 10);
  bf16_t* p = P + ((size_t)pc << 20) + ((size_t)row << 10);
  int cend = ((row >> 8) + 1) << 8;  // 256-aligned (PV K-tile width)
  bf16x8 v0 = *(const bf16x8*)(s + lane * 8);
  bf16x8 v1 = *(const bf16x8*)(s + 512 + lane * 8);
  float x[16];
  float mx = -1e30f;
#pragma unroll
  for (int j = 0; j < 8; ++j) {
    int c0 = lane * 8 + j, c1 = 512 + lane * 8 + j;
    x[j]     = (c0 <= row) ? (float)v0[j] : -1e30f;
    x[8 + j] = (c1 <= row) ? (float)v1[j] : -1e30f;
    mx = fmaxf(mx, fmaxf(x[j], x[8 + j]));
  }
  for (int o = 32; o > 0; o >>= 1) mx = fmaxf(mx, __shfl_xor(mx, o));
  float sum = 0.f;
#pragma unroll
  for (int j = 0; j < 16; ++j) {
    x[j] = (x[j] > -1e29f) ? __expf(x[j] - mx) : 0.f;
    sum += x[j];
  }
  for (int o = 32; o > 0; o >>= 1) sum += __shfl_xor(sum, o);
  float inv = 1.f / sum;
  bf16x8 o0, o1;
#pragma unroll
  for (int j = 0; j < 8; ++j) {
    o0[j] = (bf16_t)(x[j] * inv);
    o1[j] = (bf16_t)(x[8 + j] * inv);
  }
  if (lane * 8 < cend)       *(bf16x8*)(p + lane * 8) = o0;
  if (512 + lane * 8 < cend) *(bf16x8*)(p + 512 + lane * 8) = o1;
}

// ---------------- GEMM 3: O = P * V (V pre-transposed; causal-shortened K) ---------
__global__ __launch_bounds__(1024, 1) void k_pv256(const bf16_t* __restrict__ P,
                                                   const bf16_t* __restrict__ Vt,
                                                   bf16_t* __restrict__ O, int pbase) {
  __shared__ __align__(16) bf16_t lds[65536];
  int id = (int)blockIdx.x;
  int pc = id >> 4, rem = id & 15;
  int ti = rem >> 2, dj = rem & 3;
  size_t p = (size_t)(pbase + pc);
  EPI_VARS
  f32x4 acc[4][4];
  ZERO4x4(acc)
  gemm256(P + ((size_t)pc << 20) + (size_t)ti * 256 * 1024, 1024,
          Vt + (p << 20) + (size_t)dj * 256 * 1024, 1024, (ti + 1) * 4, acc, lds);
  int b = (int)(p >> 1), h = (int)(p & 1);
#pragma unroll
  for (int qm = 0; qm < 4; ++qm)
#pragma unroll
    for (int cn = 0; cn < 4; ++cn) {
      int dcol = dj * 256 + wc * 64 + cn * 16 + fr;
      f32x4 a = acc[qm][cn];
#pragma unroll
      for (int r = 0; r < 4; ++r) {
        int tk = ti * 256 + wr * 64 + qm * 16 + fq * 4 + r;
        O[(((size_t)b << 10) + tk) * 2048 + (h << 10) + dcol] = (bf16_t)a[r];
      }
    }
}

// ---------------- GEMM 4: out = O * Wo^T (fp32 out) ----------------
__global__ __launch_bounds__(1024, 1) void k_out256(const bf16_t* __restrict__ O,
                                                    const bf16_t* __restrict__ W,
                                                    float* __restrict__ out) {
  __shared__ __align__(16) bf16_t lds[65536];
  int bid = (int)blockIdx.x;
  int id = (bid & 7) * 128 + (bid >> 3);  // XCD swizzle (1024 = 8*128)
  int mt = id & 127, ntile = id >> 7;     // B-panel-major
  EPI_VARS
  f32x4 acc[4][4];
  ZERO4x4(acc)
  gemm256(O + (size_t)mt * 256 * 2048, 2048, W + (size_t)ntile * 256 * 2048, 2048, 32, acc, lds);
#pragma unroll
  for (int qm = 0; qm < 4; ++qm)
#pragma unroll
    for (int cn = 0; cn < 4; ++cn) {
      int col = ntile * 256 + wc * 64 + cn * 16 + fr;
      f32x4 a = acc[qm][cn];
#pragma unroll
      for (int r = 0; r < 4; ++r) {
        int row = mt * 256 + wr * 64 + qm * 16 + fq * 4 + r;
        out[(size_t)row * 2048 + col] = a[r];
      }
    }
}

// ---------------- launch ----------------
extern "C" void kernel_launch(void* const* d_in, const int* in_sizes, int n_in,
                              void* d_out, int out_size, void* d_ws, size_t ws_size,
                              hipStream_t stream) {
  const float* x  = (const float*)d_in[0];
  const float* Wq = (const float*)d_in[1];
  const float* bq = (const float*)d_in[2];
  const float* Wk = (const float*)d_in[3];
  const float* bk = (const float*)d_in[4];
  const float* Wv = (const float*)d_in[5];
  const float* bv = (const float*)d_in[6];
  const float* Wo = (const float*)d_in[7];
  float* out = (float*)d_out;

  const size_t MiB = 1ull << 20;
  char* w = (char*)d_ws;
  bf16_t* xb    = (bf16_t*)w;               // 128 MiB, reused as O after QKV
  bf16_t* Ob    = xb;
  bf16_t* Qb    = (bf16_t*)(w + 128 * MiB); // 128 MiB
  bf16_t* Kb    = (bf16_t*)(w + 256 * MiB); // 128 MiB
  bf16_t* Vt    = (bf16_t*)(w + 384 * MiB); // 128 MiB (transposed V)
  bf16_t* Wqkvb = (bf16_t*)(w + 512 * MiB); // 32 MiB [Wq;Wk;Wv;Wo] contiguous
  bf16_t* Wob   = (bf16_t*)(w + 536 * MiB); // = Wqkvb + 24 MiB
  bf16_t* Sc    = (bf16_t*)(w + 544 * MiB); // NP * 2 MiB (bf16; softmax in-place)

  size_t rem = ws_size > 544 * MiB ? ws_size - 544 * MiB : 0;
  int NP = (int)(rem / (2 * MiB));
  if (NP > 64) NP = 64;
  if (NP < 1) {
    k_fill<<<2048, 256, 0, stream>>>(out, (float)(ws_size >> 20), (long)out_size);
    return;
  }

  // conversions to bf16 (x; then all four weights in one launch - dst contiguous)
  k_cvt<<<2048, 256, 0, stream>>>(x, xb, 8388608L);
  k_cvtw<<<2048, 256, 0, stream>>>(Wq, Wk, Wv, Wo, Wqkvb);

  // QKV projection (Q,K normal layout; V transposed)
  k_qkv256<<<3072, 1024, 0, stream>>>(xb, Wqkvb, bq, bk, bv, Qb, Kb, Vt);

  // attention, chunked over (b,h) pairs to bound scratch (softmax in-place: P == S)
  for (int base = 0; base < 64; base += NP) {
    int np = (64 - base) < NP ? (64 - base) : NP;
    k_s256<<<np * 10, 1024, 0, stream>>>(Qb, Kb, Sc, base);
    k_softmax<<<np * 256, 256, 0, stream>>>(Sc, Sc);
    k_pv256<<<np * 16, 1024, 0, stream>>>(Sc, Vt, Ob, base);
  }

  // output projection
  k_out256<<<1024, 1024, 0, stream>>>(Ob, Wob, out);
}